// Round 1
// baseline (108.576 us; speedup 1.0000x reference)
//
#include <hip/hip_runtime.h>
#include <stdint.h>

typedef unsigned short ushort_t;
typedef __attribute__((ext_vector_type(8))) short short8v;   // 8 x bf16
typedef __attribute__((ext_vector_type(4))) float f32x4;     // MFMA acc

// ws: At bf16 [16][128][512] (2 MiB) | Wt bf16 [16][512][512] (8 MiB)
#define AT_ELEMS (16u * 128u * 512u)
#define WT_ELEMS (16u * 512u * 512u)
#define WS_NEEDED ((size_t)(AT_ELEMS + WT_ELEMS) * 2u)

__host__ __device__ constexpr int ga_sign_i(int a, int b) {
  int t = a >> 1, sw = 0;
  while (t) {
    int x = t & b;
    while (x) { sw += x & 1; x >>= 1; }
    t >>= 1;
  }
  return (sw & 1) ? -1 : 1;
}

struct SignTab { int s[16][16]; };
constexpr SignTab make_tab() {
  SignTab t{};
  for (int i = 0; i < 16; i++)
    for (int j = 0; j < 16; j++) t.s[i][j] = ga_sign_i(i, j);
  return t;
}
constexpr SignTab STAB = make_tab();

__device__ __forceinline__ ushort_t f2bf(float f) {
  unsigned u = __float_as_uint(f);
  u = (u + 0x7FFFu + ((u >> 16) & 1u)) >> 16;   // RNE
  return (ushort_t)u;
}

__device__ __forceinline__ short8v neg_bf16x8(short8v v) {
  const short m = (short)0x8000;
  return v ^ (short8v){m, m, m, m, m, m, m, m};
}

// ---------------------------------------------------------------------------
// prep (unchanged, R2-proven): At[j][b][n] = bf16(x[b,n,j]); Wt[j][u][n] = bf16(w[u,n,j])
// Reads: 64 B contiguous per thread; stores: 16 scalar bf16, lanes = consecutive n
// -> 128 B/wave per store instr.
// ---------------------------------------------------------------------------
#define PREP_XT (128 * 512)
#define PREP_TOT (PREP_XT + 512 * 512)   // 327,680 -> 1280 blocks

__global__ __launch_bounds__(256) void prep_kernel(const float* __restrict__ x,
                                                   const float* __restrict__ w,
                                                   ushort_t* __restrict__ At,
                                                   ushort_t* __restrict__ Wt) {
  int tid = blockIdx.x * 256 + threadIdx.x;
  if (tid < PREP_XT) {
    int n = tid & 511, b = tid >> 9;
    const float4* xp = (const float4*)(x + (size_t)tid * 16);
    float v[16];
#pragma unroll
    for (int qq = 0; qq < 4; qq++) {
      float4 t = xp[qq];
      v[qq * 4 + 0] = t.x; v[qq * 4 + 1] = t.y; v[qq * 4 + 2] = t.z; v[qq * 4 + 3] = t.w;
    }
#pragma unroll
    for (int j = 0; j < 16; j++)
      At[((size_t)(j * 128 + b)) * 512 + n] = f2bf(v[j]);
  } else {
    int t = tid - PREP_XT;
    int n = t & 511, u = t >> 9;
    const float4* wp = (const float4*)(w + (size_t)t * 16);
    float v[16];
#pragma unroll
    for (int qq = 0; qq < 4; qq++) {
      float4 tt = wp[qq];
      v[qq * 4 + 0] = tt.x; v[qq * 4 + 1] = tt.y; v[qq * 4 + 2] = tt.z; v[qq * 4 + 3] = tt.w;
    }
#pragma unroll
    for (int j = 0; j < 16; j++)
      Wt[((size_t)(j * 512 + u)) * 512 + n] = f2bf(v[j]);
  }
}

// ---------------------------------------------------------------------------
// gemm v2: NO LDS STAGING. Rationale: in the previous version every staged byte
// was ds_read exactly once by exactly one wave (frag n-windows are wave-private)
// -> LDS was a pass-through; all reuse is register-level (av x16, bv x16).
// So the DMA + 8 barriers + 4 vmcnt(0) drains per block (fully exposed at
// 1 wave/SIMD) were pure overhead. Now: fragments load straight from L2-resident
// At (2 MiB) / Wt (8 MiB) with the IDENTICAL lane->element map (numerics
// unchanged). bv(kt) issued at top of each kt (in-order retire => first MFMA
// waits ~vmcnt(31), already satisfied); av double-buffered one full ~5000-cyc
// MFMA phase ahead. Zero barriers in the main loop; waves fully independent
// until the epilogue cross-wave n-reduction (64 KB LDS scratch).
// VGPR ~340 (acc 64 + av 128 + bv 64 + nav 64) < 512: still 1 wave/SIMD, which
// we already had. Grid 8bt x 32ut = 256 blocks (1/CU), block = 16b x 16u x 16k,
// 4 waves split n into quarters per kt chunk of 128 n.
// ---------------------------------------------------------------------------
__global__ __launch_bounds__(256, 1) void gemm_kernel(const ushort_t* __restrict__ At,
                                                      const ushort_t* __restrict__ Wt,
                                                      const float* __restrict__ bias,
                                                      float* __restrict__ out) {
  __shared__ __align__(16) float red[16384];   // 64 KB epilogue scratch

  const int ut = blockIdx.x;       // 0..31
  const int bt = blockIdx.y;       // 0..7
  const int u0 = ut * 16, b0 = bt * 16;

  const int tid = threadIdx.x;
  const int wv = tid >> 6, lane = tid & 63;
  const int la = lane & 15, q = lane >> 4;

  // Fragment base addresses (same lane->element map as the old LDS path):
  //   A: At[(i*128 + b0+la)*512 + kt*128 + wv*32 + q*8]   (plane stride 65536)
  //   B: Wt[(j*512 + u0+la)*512 + kt*128 + wv*32 + q*8]   (plane stride 262144)
  const ushort_t* Ax = At + (size_t)(b0 + la) * 512 + wv * 32 + q * 8;
  const ushort_t* Wx = Wt + (size_t)(u0 + la) * 512 + wv * 32 + q * 8;

  f32x4 acc[16];
#pragma unroll
  for (int k = 0; k < 16; k++) acc[k] = (f32x4){0.f, 0.f, 0.f, 0.f};

  short8v av[2][16], bv[16], nav[16];

  // prologue: A frags for kt=0
#pragma unroll
  for (int i = 0; i < 16; i++)
    av[0][i] = *(const short8v*)(Ax + (size_t)i * 65536);

#pragma unroll
  for (int kt = 0; kt < 4; kt++) {
    const int cur = kt & 1, nxt = cur ^ 1;

    // B frags for this kt — oldest in flight, j-loop consumes in order.
#pragma unroll
    for (int j = 0; j < 16; j++)
      bv[j] = *(const short8v*)(Wx + (size_t)j * 262144 + kt * 128);

    // A frags for kt+1 — drain during this kt's 256-MFMA phase.
    if (kt < 3) {
#pragma unroll
      for (int i = 0; i < 16; i++)
        av[nxt][i] = *(const short8v*)(Ax + (size_t)i * 65536 + (kt + 1) * 128);
    }

#pragma unroll
    for (int i = 0; i < 16; i++) nav[i] = neg_bf16x8(av[cur][i]);

#pragma unroll
    for (int j = 0; j < 16; j++) {
#pragma unroll
      for (int k = 0; k < 16; k++) {
        const int i = j ^ k;                 // compile-time after unroll
        acc[k] = __builtin_amdgcn_mfma_f32_16x16x32_bf16(
            (STAB.s[i][j] < 0) ? nav[i] : av[cur][i], bv[j], acc[k], 0, 0, 0);
      }
    }
  }

  // --- epilogue: cross-wave n-reduction + bias + coalesced float4 out ---
#pragma unroll
  for (int g = 0; g < 4; g++) {
#pragma unroll
    for (int r2 = 0; r2 < 4; r2++) {
      float4 v = make_float4(acc[g * 4 + 0][r2], acc[g * 4 + 1][r2],
                             acc[g * 4 + 2][r2], acc[g * 4 + 3][r2]);
      int row = q * 4 + r2;                  // C/D: row = quad*4 + reg (m89)
      *(float4*)&red[(((wv * 16 + row) * 16 + la) << 4) + g * 4] = v;
    }
  }
  __syncthreads();

  const int row = tid >> 4, col = tid & 15;
  float4 o[4];
#pragma unroll
  for (int g = 0; g < 4; g++)
    o[g] = *(const float4*)&bias[(u0 + col) * 16 + g * 4];
#pragma unroll
  for (int w2 = 0; w2 < 4; w2++) {
#pragma unroll
    for (int g = 0; g < 4; g++) {
      float4 v = *(const float4*)&red[(((w2 * 16 + row) * 16 + col) << 4) + g * 4];
      o[g].x += v.x; o[g].y += v.y; o[g].z += v.z; o[g].w += v.w;
    }
  }
#pragma unroll
  for (int g = 0; g < 4; g++)
    *(float4*)&out[((size_t)(b0 + row) * 512 + (u0 + col)) * 16 + g * 4] = o[g];
}

// ---------------------------------------------------------------------------
// fallback (ws too small): exact fp32, slow but correct
// ---------------------------------------------------------------------------
__global__ __launch_bounds__(256) void naive_kernel(const float* __restrict__ x,
                                                    const float* __restrict__ w,
                                                    const float* __restrict__ bias,
                                                    float* __restrict__ out) {
  int t = blockIdx.x * 256 + threadIdx.x;
  if (t >= 128 * 512 * 16) return;
  int k = t & 15;
  int u = (t >> 4) & 511;
  int b = t >> 13;
  float sgn[16];
#pragma unroll
  for (int i = 0; i < 16; i++) sgn[i] = (float)ga_sign_i(i, i ^ k);
  float acc = bias[u * 16 + k];
  for (int n = 0; n < 512; n++) {
    const float* xp = x + ((size_t)(b * 512 + n)) * 16;
    const float* wp = w + ((size_t)(u * 512 + n)) * 16;
#pragma unroll
    for (int i = 0; i < 16; i++)
      acc += xp[i] * sgn[i] * wp[i ^ k];
  }
  out[t] = acc;
}

extern "C" void kernel_launch(void* const* d_in, const int* in_sizes, int n_in,
                              void* d_out, int out_size, void* d_ws, size_t ws_size,
                              hipStream_t stream) {
  const float* x    = (const float*)d_in[0];
  const float* w    = (const float*)d_in[1];
  const float* bias = (const float*)d_in[2];
  float* out = (float*)d_out;

  if (ws_size >= WS_NEEDED && d_ws != nullptr) {
    ushort_t* At = (ushort_t*)d_ws;
    ushort_t* Wt = At + AT_ELEMS;

    prep_kernel<<<PREP_TOT / 256, 256, 0, stream>>>(x, w, At, Wt);
    gemm_kernel<<<dim3(32, 8), 256, 0, stream>>>(At, Wt, bias, out);
  } else {
    naive_kernel<<<(128 * 512 * 16) / 256, 256, 0, stream>>>(x, w, bias, out);
  }
}